// Round 4
// baseline (693.094 us; speedup 1.0000x reference)
//
#include <hip/hip_runtime.h>
#include <math.h>

#define B_ 8
#define K4 4
#define H_ 256
#define W_ 256
#define HID_ 16
#define DT_ 0.1f
#define STEPS_ 12
#define OMEGA_ 0.9f
#define D_MAX_ 2.0f
#define CHI_MAX_ 2.0f
#define HW_ (H_ * W_)

__device__ __forceinline__ int clampi(int v, int lo, int hi) { return min(max(v, lo), hi); }

__device__ __forceinline__ float softplus_f(float x) {
    return fmaxf(x, 0.0f) + log1pf(expf(-fabsf(x)));
}

union F4 { float4 v; float f[4]; };
union F2 { float2 v; float f[2]; };

__device__ __forceinline__ F4 sel4(bool c, const F4& a, const F4& b) {
    F4 r;
    r.f[0] = c ? a.f[0] : b.f[0];
    r.f[1] = c ? a.f[1] : b.f[1];
    r.f[2] = c ? a.f[2] : b.f[2];
    r.f[3] = c ? a.f[3] : b.f[3];
    return r;
}

// ---------------- setup: params + weight transpose ----------------
__global__ void setup_kernel(const float* __restrict__ D_raw,
                             const float* __restrict__ chi_raw,
                             const float* __restrict__ cap_logit,
                             const float* __restrict__ w1,
                             const float* __restrict__ w2,
                             float* __restrict__ params,
                             float* __restrict__ w1t,
                             float* __restrict__ w2t) {
    int tid = threadIdx.x;
    if (tid == 0) {
        for (int c = 0; c < K4; ++c) {
            float d = fminf(softplus_f(D_raw[c]) + 1e-8f, D_MAX_);
            params[c]      = d;
            params[6 + c]  = DT_ * d;
            params[10 + c] = OMEGA_ / (1.0f + DT_ * d * 4.0f);
        }
        params[4] = fminf(softplus_f(chi_raw[0]) + 1e-8f, CHI_MAX_);
        float ct = 1.0f / (1.0f + expf(-cap_logit[0]));
        params[5] = fminf(fmaxf(ct, 0.001f), 0.95f);
    }
    for (int i = tid; i < 576; i += 256) {
        int o = i & 15, rest = i >> 4, ic = rest / 9, k = rest % 9;
        w1t[i] = w1[(o * K4 + ic) * 9 + k];
    }
    for (int i = tid; i < 2304; i += 256) {
        int o = i & 15, rest = i >> 4, ic = rest / 9, k = rest % 9;
        w2t[i] = w2[(o * HID_ + ic) * 9 + k];
    }
}

// ---------------- fused CNN, 16x16 tiles ----------------
#define PS2_(c,ry,rx) csmem[((c)*20 + (ry))*24 + (rx)]
#define HS2_(o,ry,rx) csmem[1920 + ((o)*18 + (ry))*21 + (rx)]

__global__ __launch_bounds__(256) void cnn_kernel(const float* __restrict__ p0,
                                                  const float* __restrict__ w1t,
                                                  const float* __restrict__ b1,
                                                  const float* __restrict__ w2t,
                                                  const float* __restrict__ b2,
                                                  const float* __restrict__ w3,
                                                  const float* __restrict__ b3,
                                                  float* __restrict__ kmap) {
    __shared__ float csmem[1920 + 16 * 18 * 21];
    const int tid = threadIdx.x;
    const int tx0 = blockIdx.x * 16, ty0 = blockIdx.y * 16, b = blockIdx.z;

    for (int i = tid; i < 4 * 20 * 20; i += 256) {
        int c = i / 400, r = i % 400;
        int ry = r / 20, rx = r % 20;
        int gy = ty0 + ry - 2, gx = tx0 + rx - 2;
        float v = 0.0f;
        if ((unsigned)gy < 256u && (unsigned)gx < 256u)
            v = p0[(((size_t)b * K4 + c) << 16) + gy * W_ + gx];
        PS2_(c, ry, rx) = v;
    }
    __syncthreads();

    for (int i = tid; i < 18 * 18; i += 256) {
        int iy = i / 18, ixx = i % 18;
        int gy = ty0 + iy - 1, gx = tx0 + ixx - 1;
        bool indom = ((unsigned)gy < 256u) && ((unsigned)gx < 256u);
        float acc[HID_];
#pragma unroll
        for (int o = 0; o < HID_; ++o) acc[o] = b1[o];
        for (int ic = 0; ic < K4; ++ic)
            for (int ky = 0; ky < 3; ++ky)
#pragma unroll
                for (int kx = 0; kx < 3; ++kx) {
                    float v = PS2_(ic, iy + ky, ixx + kx);
                    const float* wp = w1t + (ic * 9 + ky * 3 + kx) * 16;
#pragma unroll
                    for (int o = 0; o < HID_; ++o)
                        acc[o] = fmaf(wp[o], v, acc[o]);
                }
#pragma unroll
        for (int o = 0; o < HID_; ++o)
            HS2_(o, iy, ixx) = indom ? fmaxf(acc[o], 0.0f) : 0.0f;
    }
    __syncthreads();

    {
        int iy2 = tid >> 4, ix2 = tid & 15;
        float acc[HID_];
#pragma unroll
        for (int o = 0; o < HID_; ++o) acc[o] = b2[o];
        for (int ic = 0; ic < HID_; ++ic)
            for (int ky = 0; ky < 3; ++ky)
#pragma unroll
                for (int kx = 0; kx < 3; ++kx) {
                    float v = HS2_(ic, iy2 + ky, ix2 + kx);
                    const float* wp = w2t + (ic * 9 + ky * 3 + kx) * 16;
#pragma unroll
                    for (int o = 0; o < HID_; ++o)
                        acc[o] = fmaf(wp[o], v, acc[o]);
                }
        float s = b3[0];
#pragma unroll
        for (int o = 0; o < HID_; ++o)
            s += w3[o] * fmaxf(acc[o], 0.0f);
        float km = 1.0f / (1.0f + expf(-s));
        km = fmaxf(km, 1e-6f);
        kmap[((size_t)b << 16) + (ty0 + iy2) * W_ + tx0 + ix2] = km;
    }
}

// ---------------- fused step: register-block Jacobi ----------------
// Tile 64x32. Jacobi region rel [-8..71]x[-8..39] = 80x48 -> 20x12 thread
// blocks of 4x4 px, all 4 channels in registers. p region (for rhs +2
// forward halo) rel [-8..73]x[-8..41] = 82x50, staged in LDS phase 1.
// Phase 2 overlays LDS with double-buffered boundary arrays:
//   RB rows: [2][4][24][88], CB cols (transposed f4): [2][4][2][12][21][4]
#define PL_(c,r,x)      smem[((c)*50 + (r))*84 + (x)]
#define RB_(bf,c,s,x)   smem[(bf)*8448 + ((c)*24 + (s))*88 + (x)]
#define CBIDX(bf,c,side,i,j) (16896 + (bf)*8064 + ((((c)*2 + (side))*12 + (i))*21 + (j))*4)
#define STEP_LDS (33024 * 4)

__global__ __launch_bounds__(256, 1) void step_kernel(const float* __restrict__ pin,
                                                      float* __restrict__ pout,
                                                      const float* __restrict__ kmap,
                                                      const float* __restrict__ params,
                                                      const int* __restrict__ tumor_idx,
                                                      int first) {
    extern __shared__ float smem[];
    const int tid = threadIdx.x;
    const int tx0 = blockIdx.x * 64, ty0 = blockIdx.y * 32, b = blockIdx.z;

    // ---- phase 1: load p region [4][50][82] (edge-replicate clamp)
    for (int idx = tid; idx < 4 * 50 * 82; idx += 256) {
        int c = idx / 4100, r2 = idx % 4100;
        int r = r2 / 82, x = r2 % 82;
        int gy = clampi(ty0 + r - 8, 0, 255);
        int gx = clampi(tx0 + x - 8, 0, 255);
        float v = pin[(((size_t)b * K4 + c) << 16) + gy * W_ + gx];
        if (first) v = fmaxf(v, 0.0f);
        PL_(c, r, x) = v;
    }
    __syncthreads();

    const bool act = (tid < 240);
    const int i = tid / 20, j = tid % 20;
    const int gy0 = ty0 + 4 * i - 8;
    const int gx0 = tx0 + 4 * j - 8;
    const bool upSelf = (gy0 == 0), dnSelf = (gy0 + 3 == 255);
    const bool lm = (gx0 == 0), rm = (gx0 + 3 == 255);

    float dtD[4], wod[4];
#pragma unroll
    for (int c = 0; c < 4; ++c) { dtD[c] = params[6 + c]; wod[c] = params[10 + c]; }
    const float chi = params[4], cap = params[5];
    const int ti = tumor_idx[0];

    F4 cur[4][4], rsv[4][4];

    if (act) {
        F2 hx[4][4];
        F4 vx[4][2];
#pragma unroll
        for (int c = 0; c < 4; ++c) {
#pragma unroll
            for (int k = 0; k < 4; ++k) {
                cur[c][k].v = *(const float4*)&PL_(c, 4 * i + k, 4 * j);
                hx[c][k].v  = *(const float2*)&PL_(c, 4 * i + k, 4 * j + 4);
            }
            vx[c][0].v = *(const float4*)&PL_(c, 4 * i + 4, 4 * j);
            vx[c][1].v = *(const float4*)&PL_(c, 4 * i + 5, 4 * j);
        }
        const float* kb = kmap + ((size_t)b << 16);
        // ---- rhs (exact reference arithmetic order)
#pragma unroll
        for (int k = 0; k < 4; ++k) {
            int gy = gy0 + k;
            int cy = clampi(gy, 0, 255);
#pragma unroll
            for (int jj = 0; jj < 4; ++jj) {
                int gx = gx0 + jj;
                int cx = clampi(gx, 0, 255);
                float pc[4], px1[4], py1[4], g0x[4], g1x[4], g0y[4], g1y[4];
                float s0x = 0.f, s1x = 0.f, s0y = 0.f, s1y = 0.f;
#pragma unroll
                for (int c = 0; c < 4; ++c) {
                    float pcv = cur[c][k].f[jj];
                    float a  = (jj < 3) ? cur[c][k].f[jj + 1] : hx[c][k].f[0];
                    float bb = (jj == 0) ? cur[c][k].f[2]
                             : (jj == 1) ? cur[c][k].f[3]
                             : (jj == 2) ? hx[c][k].f[0] : hx[c][k].f[1];
                    float d  = (k < 3) ? cur[c][k + 1].f[jj] : vx[c][0].f[jj];
                    float e  = (k < 2) ? cur[c][k + 2].f[jj]
                             : (k == 2) ? vx[c][0].f[jj] : vx[c][1].f[jj];
                    pc[c] = pcv; px1[c] = a; py1[c] = d;
                    g0x[c] = a - pcv;  g1x[c] = bb - a;
                    g0y[c] = d - pcv;  g1y[c] = e - d;
                    s0x += g0x[c]; s1x += g1x[c]; s0y += g0y[c]; s1y += g1y[c];
                }
                float km = kb[cy * W_ + cx];
#pragma unroll
                for (int c = 0; c < 4; ++c) {
                    float fx0 = -chi * pc[c]  * (s0x - g0x[c]);
                    float fx1 = -chi * px1[c] * (s1x - g1x[c]);
                    float fy0 = -chi * pc[c]  * (s0y - g0y[c]);
                    float fy1 = -chi * py1[c] * (s1y - g1y[c]);
                    float cross = (fx0 - fx1) + (fy0 - fy1);
                    float react = 0.0f;
                    if (c == ti) {
                        float pt = fminf(fmaxf(pc[c], 0.0f), 1.0f);
                        react = km * pt * (1.0f - pt / cap);
                    }
                    rsv[c][k].f[jj] = pc[c] + DT_ * (cross + react);
                }
            }
        }
    }
    __syncthreads();   // all PL reads done; overlay LDS with boundary bufs

    const int su = clampi(2 * i - 1, 0, 23);
    const int sd = clampi(2 * i + 2, 0, 23);
    const int jm1 = max(j - 1, 0);
    const int jp1 = j + 1;   // <= 20, in-bounds (garbage slot by design)

    // ---- publish initial boundaries into buf 0
    if (act) {
#pragma unroll
        for (int c = 0; c < 4; ++c) {
            *(float4*)&RB_(0, c, 2 * i,     4 * j) = cur[c][0].v;
            *(float4*)&RB_(0, c, 2 * i + 1, 4 * j) = cur[c][3].v;
            F4 c0, c3;
#pragma unroll
            for (int k = 0; k < 4; ++k) { c0.f[k] = cur[c][k].f[0]; c3.f[k] = cur[c][k].f[3]; }
            *(float4*)&smem[CBIDX(0, c, 0, i, j)] = c0.v;
            *(float4*)&smem[CBIDX(0, c, 1, i, j)] = c3.v;
        }
    }
    __syncthreads();

    // ---- 8 damped-Jacobi sweeps
#pragma unroll
    for (int it = 0; it < 8; ++it) {
        const int rb = it & 1, wb = rb ^ 1;
        F4 nc[4][4];
        if (act) {
#pragma unroll
            for (int c = 0; c < 4; ++c) {
                F4 up4, dn4, lc, rc;
                up4.v = *(const float4*)&RB_(rb, c, su, 4 * j);
                dn4.v = *(const float4*)&RB_(rb, c, sd, 4 * j);
                lc.v  = *(const float4*)&smem[CBIDX(rb, c, 1, i, jm1)];
                rc.v  = *(const float4*)&smem[CBIDX(rb, c, 0, i, jp1)];
#pragma unroll
                for (int k = 0; k < 4; ++k) {
                    F4 cv = cur[c][k];
                    F4 up = (k == 0) ? sel4(upSelf, cv, up4) : cur[c][k - 1];
                    F4 dn = (k == 3) ? sel4(dnSelf, cv, dn4) : cur[c][k + 1];
                    float lf = lm ? cv.f[0] : lc.f[k];
                    float rt = rm ? cv.f[3] : rc.f[k];
                    F4 o;
#pragma unroll
                    for (int jj = 0; jj < 4; ++jj) {
                        float l  = (jj == 0) ? lf : cv.f[jj - 1];
                        float rr = (jj == 3) ? rt : cv.f[jj + 1];
                        float lap = up.f[jj] + dn.f[jj] + l + rr - 4.0f * cv.f[jj];
                        float r_ = rsv[c][k].f[jj] - (cv.f[jj] - dtD[c] * lap);
                        o.f[jj] = cv.f[jj] + wod[c] * r_;
                    }
                    nc[c][k] = o;
                }
            }
        }
        if (it < 7) {
            if (act) {
#pragma unroll
                for (int c = 0; c < 4; ++c) {
                    *(float4*)&RB_(wb, c, 2 * i,     4 * j) = nc[c][0].v;
                    *(float4*)&RB_(wb, c, 2 * i + 1, 4 * j) = nc[c][3].v;
                    F4 c0, c3;
#pragma unroll
                    for (int k = 0; k < 4; ++k) { c0.f[k] = nc[c][k].f[0]; c3.f[k] = nc[c][k].f[3]; }
                    *(float4*)&smem[CBIDX(wb, c, 0, i, j)] = c0.v;
                    *(float4*)&smem[CBIDX(wb, c, 1, i, j)] = c3.v;
                }
            }
            __syncthreads();
        }
        if (act) {
#pragma unroll
            for (int c = 0; c < 4; ++c)
#pragma unroll
                for (int k = 0; k < 4; ++k)
                    cur[c][k] = nc[c][k];
        }
    }

    // ---- simplex projection (exact reference replication) + store
    if (act && i >= 2 && i < 10 && j >= 2 && j < 18) {
#pragma unroll
        for (int k = 0; k < 4; ++k) {
            F4 res[4];
#pragma unroll
            for (int jj = 0; jj < 4; ++jj) {
                float v0 = cur[0][k].f[jj], v1 = cur[1][k].f[jj];
                float v2 = cur[2][k].f[jj], v3 = cur[3][k].f[jj];
                float u0 = v0, u1 = v1, u2 = v2, u3 = v3, t;
                t = fmaxf(u0, u1); u1 = fminf(u0, u1); u0 = t;
                t = fmaxf(u2, u3); u3 = fminf(u2, u3); u2 = t;
                t = fmaxf(u0, u2); u2 = fminf(u0, u2); u0 = t;
                t = fmaxf(u1, u3); u3 = fminf(u1, u3); u1 = t;
                t = fmaxf(u1, u2); u2 = fminf(u1, u2); u1 = t;
                float cs1 = u0 + u1;
                float cs2 = cs1 + u2;
                float c0 = u0 - 1.0f;
                float c1 = cs1 - 1.0f;
                float c2 = cs2 - 1.0f;
                int rho = 0;
                if (u1 - c1 / 2.0f > 0.0f) rho = 1;
                if (u2 - c2 / 3.0f > 0.0f) rho = 2;
                if (u3 - (cs2 + u3 - 1.0f) / 4.0f > 0.0f) rho = 3;
                int ri = rho - 1; if (ri < 0) ri = 0;
                float tau = (ri == 0) ? c0 : (ri == 1) ? (c1 / 2.0f) : (c2 / 3.0f);
                float w0 = fmaxf(v0 - tau, 0.0f);
                float w1 = fmaxf(v1 - tau, 0.0f);
                float w2 = fmaxf(v2 - tau, 0.0f);
                float w3 = fmaxf(v3 - tau, 0.0f);
                float inv = 1.0f / (w0 + w1 + w2 + w3 + 1e-8f);
                res[0].f[jj] = w0 * inv;
                res[1].f[jj] = w1 * inv;
                res[2].f[jj] = w2 * inv;
                res[3].f[jj] = w3 * inv;
            }
            int oy = gy0 + k, ox = gx0;
#pragma unroll
            for (int c = 0; c < 4; ++c)
                *(float4*)&pout[(((size_t)b * K4 + c) << 16) + oy * W_ + ox] = res[c].v;
        }
    }
}

extern "C" void kernel_launch(void* const* d_in, const int* in_sizes, int n_in,
                              void* d_out, int out_size, void* d_ws, size_t ws_size,
                              hipStream_t stream) {
    const float* p0        = (const float*)d_in[0];
    const float* D_raw     = (const float*)d_in[1];
    const float* chi_raw   = (const float*)d_in[2];
    const float* cap_logit = (const float*)d_in[4];
    const float* w1        = (const float*)d_in[5];
    const float* b1        = (const float*)d_in[6];
    const float* w2        = (const float*)d_in[7];
    const float* b2        = (const float*)d_in[8];
    const float* w3        = (const float*)d_in[9];
    const float* b3        = (const float*)d_in[10];
    const int*   tumor_idx = (const int*)d_in[11];

    const size_t NP = (size_t)B_ * K4 * HW_;
    char* ws = (char*)d_ws;
    float* params = (float*)(ws + 0);
    float* w1t    = (float*)(ws + 1024);
    float* w2t    = (float*)(ws + 4096);
    float* kmap   = (float*)(ws + 16384);
    float* pA     = (float*)(ws + 4  * 1024 * 1024);
    float* pB     = (float*)(ws + 12 * 1024 * 1024);
    float* out    = (float*)d_out;

    hipFuncSetAttribute((const void*)step_kernel,
                        hipFuncAttributeMaxDynamicSharedMemorySize, STEP_LDS);

    setup_kernel<<<1, 256, 0, stream>>>(D_raw, chi_raw, cap_logit, w1, w2,
                                        params, w1t, w2t);
    dim3 cgrid(16, 16, B_);
    cnn_kernel<<<cgrid, 256, 0, stream>>>(p0, w1t, b1, w2t, b2, w3, b3, kmap);

    dim3 sgrid(4, 8, B_);
    float* bufs[2] = {pA, pB};
    for (int s = 0; s < STEPS_; ++s) {
        const float* pin = (s == 0) ? p0 : bufs[(s - 1) & 1];
        float* pout = (s == STEPS_ - 1) ? out : bufs[s & 1];
        step_kernel<<<sgrid, 256, STEP_LDS, stream>>>(pin, pout, kmap, params,
                                                      tumor_idx, s == 0 ? 1 : 0);
    }
}

// Round 5
// 611.501 us; speedup vs baseline: 1.1334x; 1.1334x over previous
//
#include <hip/hip_runtime.h>
#include <math.h>

#define B_ 8
#define K4 4
#define H_ 256
#define W_ 256
#define HID_ 16
#define DT_ 0.1f
#define STEPS_ 12
#define OMEGA_ 0.9f
#define D_MAX_ 2.0f
#define CHI_MAX_ 2.0f
#define HW_ (H_ * W_)

__device__ __forceinline__ int clampi(int v, int lo, int hi) { return min(max(v, lo), hi); }

__device__ __forceinline__ float softplus_f(float x) {
    return fmaxf(x, 0.0f) + log1pf(expf(-fabsf(x)));
}

// ---------------- setup: params + weight transpose ----------------
__global__ void setup_kernel(const float* __restrict__ D_raw,
                             const float* __restrict__ chi_raw,
                             const float* __restrict__ cap_logit,
                             const float* __restrict__ w1,
                             const float* __restrict__ w2,
                             float* __restrict__ params,
                             float* __restrict__ w1t,
                             float* __restrict__ w2t) {
    int tid = threadIdx.x;
    if (tid == 0) {
        for (int c = 0; c < K4; ++c) {
            float d = fminf(softplus_f(D_raw[c]) + 1e-8f, D_MAX_);
            params[c]      = d;
            params[6 + c]  = DT_ * d;
            params[10 + c] = OMEGA_ / (1.0f + DT_ * d * 4.0f);
        }
        params[4] = fminf(softplus_f(chi_raw[0]) + 1e-8f, CHI_MAX_);
        float ct = 1.0f / (1.0f + expf(-cap_logit[0]));
        params[5] = fminf(fmaxf(ct, 0.001f), 0.95f);
    }
    for (int i = tid; i < 576; i += 256) {
        int o = i & 15, rest = i >> 4, ic = rest / 9, k = rest % 9;
        w1t[i] = w1[(o * K4 + ic) * 9 + k];
    }
    for (int i = tid; i < 2304; i += 256) {
        int o = i & 15, rest = i >> 4, ic = rest / 9, k = rest % 9;
        w2t[i] = w2[(o * HID_ + ic) * 9 + k];
    }
}

// ---------------- fused CNN, 16(rows)x32(cols) tiles, 2 px/thread in conv2 ----
// PS [4][20][36]; HS [16][18][40] (stride 40 -> row bank offsets 0/8/16/24, 2-way max)
#define PS2_(c,ry,rx) csmem[((c)*20 + (ry))*36 + (rx)]
#define HS2_(o,ry,rx) csmem[2880 + ((o)*18 + (ry))*40 + (rx)]

__global__ __launch_bounds__(256) void cnn_kernel(const float* __restrict__ p0,
                                                  const float* __restrict__ w1t,
                                                  const float* __restrict__ b1,
                                                  const float* __restrict__ w2t,
                                                  const float* __restrict__ b2,
                                                  const float* __restrict__ w3,
                                                  const float* __restrict__ b3,
                                                  float* __restrict__ kmap) {
    __shared__ float csmem[2880 + 16 * 18 * 40];
    const int tid = threadIdx.x;
    const int tx0 = blockIdx.x * 32, ty0 = blockIdx.y * 16, b = blockIdx.z;

    // p0 tile rel y[-2..17] x[-2..33], zero-pad outside domain
    for (int i = tid; i < 4 * 20 * 36; i += 256) {
        int c = i / 720, r = i % 720;
        int ry = r / 36, rx = r % 36;
        int gy = ty0 + ry - 2, gx = tx0 + rx - 2;
        float v = 0.0f;
        if ((unsigned)gy < 256u && (unsigned)gx < 256u)
            v = p0[(((size_t)b * K4 + c) << 16) + gy * W_ + gx];
        PS2_(c, ry, rx) = v;
    }
    __syncthreads();

    // conv1 on rel y[-1..16] x[-1..32]: 18x34 = 612 items
    for (int i = tid; i < 18 * 34; i += 256) {
        int iy = i / 34, ixx = i % 34;
        int gy = ty0 + iy - 1, gx = tx0 + ixx - 1;
        bool indom = ((unsigned)gy < 256u) && ((unsigned)gx < 256u);
        float acc[HID_];
#pragma unroll
        for (int o = 0; o < HID_; ++o) acc[o] = b1[o];
        for (int ic = 0; ic < K4; ++ic)
            for (int ky = 0; ky < 3; ++ky)
#pragma unroll
                for (int kx = 0; kx < 3; ++kx) {
                    float v = PS2_(ic, iy + ky, ixx + kx);
                    const float* wp = w1t + (ic * 9 + ky * 3 + kx) * 16;
#pragma unroll
                    for (int o = 0; o < HID_; ++o)
                        acc[o] = fmaf(wp[o], v, acc[o]);
                }
#pragma unroll
        for (int o = 0; o < HID_; ++o)
            HS2_(o, iy, ixx) = indom ? fmaxf(acc[o], 0.0f) : 0.0f;
    }
    __syncthreads();

    // conv2 + relu + 1x1 + sigmoid; 512 px, 2 px per thread (cols ix and ix+16)
    {
        int iy2 = tid >> 4, ix2 = tid & 15;
        float accA[HID_], accB[HID_];
#pragma unroll
        for (int o = 0; o < HID_; ++o) { accA[o] = b2[o]; accB[o] = b2[o]; }
        for (int ic = 0; ic < HID_; ++ic)
            for (int ky = 0; ky < 3; ++ky)
#pragma unroll
                for (int kx = 0; kx < 3; ++kx) {
                    float vA = HS2_(ic, iy2 + ky, ix2 + kx);
                    float vB = HS2_(ic, iy2 + ky, ix2 + 16 + kx);
                    const float* wp = w2t + (ic * 9 + ky * 3 + kx) * 16;
#pragma unroll
                    for (int o = 0; o < HID_; ++o) {
                        accA[o] = fmaf(wp[o], vA, accA[o]);
                        accB[o] = fmaf(wp[o], vB, accB[o]);
                    }
                }
        float sA = b3[0], sB = b3[0];
#pragma unroll
        for (int o = 0; o < HID_; ++o) {
            sA += w3[o] * fmaxf(accA[o], 0.0f);
            sB += w3[o] * fmaxf(accB[o], 0.0f);
        }
        float kmA = fmaxf(1.0f / (1.0f + expf(-sA)), 1e-6f);
        float kmB = fmaxf(1.0f / (1.0f + expf(-sB)), 1e-6f);
        size_t rowb = ((size_t)b << 16) + (ty0 + iy2) * W_;
        kmap[rowb + tx0 + ix2]      = kmA;
        kmap[rowb + tx0 + ix2 + 16] = kmB;
    }
}

// ---------------- fused step: rhs(+init) + 8 Jacobi + projection ----------------
// tile 64x32, region x rel [-8..73] (82 cols @ +12 -> ix 4..85),
//                  y rel [-8..41] (50 rows @ +9 -> row 1..50)
// XS[2][4][52][92] double-buffered = 153,088 B (stride 92 -> bank shift 28)
#define XSSTR 92
#define XSBUF (4 * 52 * XSSTR)
#define XS_(buf,c,row,col) smem[(buf)*XSBUF + ((c)*52 + (row))*XSSTR + (col)]
#define STEP_LDS (2 * XSBUF * 4)

__global__ __launch_bounds__(1024) void step_kernel(const float* __restrict__ pin,
                                                    float* __restrict__ pout,
                                                    const float* __restrict__ kmap,
                                                    const float* __restrict__ params,
                                                    const int* __restrict__ tumor_idx,
                                                    int first) {
    extern __shared__ float smem[];
    const int tid = threadIdx.x;
    const int tx0 = blockIdx.x * 64, ty0 = blockIdx.y * 32, b = blockIdx.z;

    // ---- load p region into XS[0]
    for (int i = tid; i < 4 * 50 * 82; i += 1024) {
        int c = i / 4100, r = i % 4100;
        int ry = r / 82, rx = r % 82;
        int gy = clampi(ty0 + ry - 8, 0, 255);
        int gx = clampi(tx0 + rx - 8, 0, 255);
        float v = pin[(((size_t)b * K4 + c) << 16) + gy * W_ + gx];
        if (first) v = fmaxf(v, 0.0f);
        XS_(0, c, ry + 1, rx + 4) = v;
    }
    __syncthreads();

    const bool act = (tid < 960);
    const int ry_it = tid / 20, g = tid % 20;  // 48 rows x 20 strips
    const int gy = ty0 + ry_it - 8;
    const int gx0 = tx0 + 4 * g - 8;
    const int yc = ry_it + 1;
    const int yu = clampi(gy - 1, 0, 255) - ty0 + 9;
    const int yd = clampi(gy + 1, 0, 255) - ty0 + 9;
    const int ix = 4 + 4 * g;
    const bool lm = (gx0 == 0), rm = (gx0 == 252);

    float dtD[4], wod[4];
#pragma unroll
    for (int c = 0; c < 4; ++c) { dtD[c] = params[6 + c]; wod[c] = params[10 + c]; }
    const float chi = params[4], cap = params[5];
    const int ti = tumor_idx[0];

    float4 ce[4];
    float4 rsv[4];
    if (act) {
#pragma unroll
        for (int c = 0; c < 4; ++c)
            ce[c] = *(const float4*)&XS_(0, c, yc, ix);

        // ---- rhs for my 4-px strip (reference arithmetic order)
        const int cy = clampi(gy, 0, 255);
        const int y1 = clampi(gy + 1, 0, 255);
        const int y2 = clampi(gy + 2, 0, 255);
        const int rowc = cy - ty0 + 9, row1 = y1 - ty0 + 9, row2 = y2 - ty0 + 9;
        float rsvf[4][4];
        float cef[4][4];
#pragma unroll
        for (int c = 0; c < 4; ++c) {
            cef[c][0] = ce[c].x; cef[c][1] = ce[c].y;
            cef[c][2] = ce[c].z; cef[c][3] = ce[c].w;
        }
#pragma unroll
        for (int k = 0; k < 4; ++k) {
            int gxk = gx0 + k;
            int cx = clampi(gxk, 0, 255);
            int x1 = clampi(gxk + 1, 0, 255);
            int x2 = clampi(gxk + 2, 0, 255);
            int col1 = x1 - tx0 + 12, col2 = x2 - tx0 + 12;
            float pc[4], px1[4], py1[4], g0x[4], g1x[4], g0y[4], g1y[4];
            float s0x = 0.f, s1x = 0.f, s0y = 0.f, s1y = 0.f;
#pragma unroll
            for (int c = 0; c < 4; ++c) {
                float pcv = cef[c][k];
                float a   = XS_(0, c, rowc, col1);
                float bb  = XS_(0, c, rowc, col2);
                float d   = XS_(0, c, row1, (cx - tx0 + 12));
                float e   = XS_(0, c, row2, (cx - tx0 + 12));
                pc[c] = pcv; px1[c] = a; py1[c] = d;
                g0x[c] = a - pcv;  g1x[c] = bb - a;
                g0y[c] = d - pcv;  g1y[c] = e - d;
                s0x += g0x[c]; s1x += g1x[c]; s0y += g0y[c]; s1y += g1y[c];
            }
            float km = kmap[((size_t)b << 16) + cy * W_ + cx];
#pragma unroll
            for (int c = 0; c < 4; ++c) {
                float fx0 = -chi * pc[c]  * (s0x - g0x[c]);
                float fx1 = -chi * px1[c] * (s1x - g1x[c]);
                float fy0 = -chi * pc[c]  * (s0y - g0y[c]);
                float fy1 = -chi * py1[c] * (s1y - g1y[c]);
                float cross = (fx0 - fx1) + (fy0 - fy1);
                float react = 0.0f;
                if (c == ti) {
                    float pt = fminf(fmaxf(pc[c], 0.0f), 1.0f);
                    react = km * pt * (1.0f - pt / cap);
                }
                rsvf[c][k] = pc[c] + DT_ * (cross + react);
            }
        }
#pragma unroll
        for (int c = 0; c < 4; ++c) {
            rsv[c].x = rsvf[c][0]; rsv[c].y = rsvf[c][1];
            rsv[c].z = rsvf[c][2]; rsv[c].w = rsvf[c][3];
        }
    }

    // ---- 8 damped-Jacobi sweeps; center strip lives in ce[] registers
#pragma unroll
    for (int j = 0; j < 8; ++j) {
        const int rb = j & 1;
        float4 o[4];
        if (act) {
#pragma unroll
            for (int c = 0; c < 4; ++c) {
                float4 up = *(const float4*)&XS_(rb, c, yu, ix);
                float4 dn = *(const float4*)&XS_(rb, c, yd, ix);
                float lf = XS_(rb, c, yc, ix - 1);
                float rt = XS_(rb, c, yc, ix + 4);
                float4 cv = ce[c];
                float l0 = lm ? cv.x : lf;
                float r3 = rm ? cv.w : rt;
                float4 ov;
                {
                    float lap = up.x + dn.x + l0 + cv.y - 4.0f * cv.x;
                    float r = rsv[c].x - (cv.x - dtD[c] * lap);
                    ov.x = cv.x + wod[c] * r;
                }
                {
                    float lap = up.y + dn.y + cv.x + cv.z - 4.0f * cv.y;
                    float r = rsv[c].y - (cv.y - dtD[c] * lap);
                    ov.y = cv.y + wod[c] * r;
                }
                {
                    float lap = up.z + dn.z + cv.y + cv.w - 4.0f * cv.z;
                    float r = rsv[c].z - (cv.z - dtD[c] * lap);
                    ov.z = cv.z + wod[c] * r;
                }
                {
                    float lap = up.w + dn.w + cv.z + r3 - 4.0f * cv.w;
                    float r = rsv[c].w - (cv.w - dtD[c] * lap);
                    ov.w = cv.w + wod[c] * r;
                }
                o[c] = ov;
            }
        }
        if (j < 7) {
            if (act) {
#pragma unroll
                for (int c = 0; c < 4; ++c)
                    *(float4*)&XS_((rb ^ 1), c, yc, ix) = o[c];
            }
            __syncthreads();
        }
        if (act) {
#pragma unroll
            for (int c = 0; c < 4; ++c) ce[c] = o[c];
        }
    }

    // ---- simplex projection (exact reference replication) + store
    if (act && ry_it >= 8 && ry_it < 40 && g >= 2 && g < 18) {
        float cef[4][4], res[4][4];
#pragma unroll
        for (int c = 0; c < 4; ++c) {
            cef[c][0] = ce[c].x; cef[c][1] = ce[c].y;
            cef[c][2] = ce[c].z; cef[c][3] = ce[c].w;
        }
#pragma unroll
        for (int k = 0; k < 4; ++k) {
            float v0 = cef[0][k], v1 = cef[1][k], v2 = cef[2][k], v3 = cef[3][k];
            float u0 = v0, u1 = v1, u2 = v2, u3 = v3, t;
            t = fmaxf(u0, u1); u1 = fminf(u0, u1); u0 = t;
            t = fmaxf(u2, u3); u3 = fminf(u2, u3); u2 = t;
            t = fmaxf(u0, u2); u2 = fminf(u0, u2); u0 = t;
            t = fmaxf(u1, u3); u3 = fminf(u1, u3); u1 = t;
            t = fmaxf(u1, u2); u2 = fminf(u1, u2); u1 = t;
            float cs1 = u0 + u1;
            float cs2 = cs1 + u2;
            float c0 = u0 - 1.0f;
            float c1 = cs1 - 1.0f;
            float c2 = cs2 - 1.0f;
            int rho = 0;
            if (u1 - c1 / 2.0f > 0.0f) rho = 1;
            if (u2 - c2 / 3.0f > 0.0f) rho = 2;
            if (u3 - (cs2 + u3 - 1.0f) / 4.0f > 0.0f) rho = 3;
            int ri = rho - 1; if (ri < 0) ri = 0;
            float tau = (ri == 0) ? c0 : (ri == 1) ? (c1 / 2.0f) : (c2 / 3.0f);
            float w0 = fmaxf(v0 - tau, 0.0f);
            float w1 = fmaxf(v1 - tau, 0.0f);
            float w2 = fmaxf(v2 - tau, 0.0f);
            float w3 = fmaxf(v3 - tau, 0.0f);
            float inv = 1.0f / (w0 + w1 + w2 + w3 + 1e-8f);
            res[0][k] = w0 * inv;
            res[1][k] = w1 * inv;
            res[2][k] = w2 * inv;
            res[3][k] = w3 * inv;
        }
        int oy = ty0 + ry_it - 8;
        int ox = tx0 + 4 * g - 8;
#pragma unroll
        for (int c = 0; c < 4; ++c) {
            float4 rv;
            rv.x = res[c][0]; rv.y = res[c][1]; rv.z = res[c][2]; rv.w = res[c][3];
            *(float4*)&pout[(((size_t)b * K4 + c) << 16) + oy * W_ + ox] = rv;
        }
    }
}

extern "C" void kernel_launch(void* const* d_in, const int* in_sizes, int n_in,
                              void* d_out, int out_size, void* d_ws, size_t ws_size,
                              hipStream_t stream) {
    const float* p0        = (const float*)d_in[0];
    const float* D_raw     = (const float*)d_in[1];
    const float* chi_raw   = (const float*)d_in[2];
    const float* cap_logit = (const float*)d_in[4];
    const float* w1        = (const float*)d_in[5];
    const float* b1        = (const float*)d_in[6];
    const float* w2        = (const float*)d_in[7];
    const float* b2        = (const float*)d_in[8];
    const float* w3        = (const float*)d_in[9];
    const float* b3        = (const float*)d_in[10];
    const int*   tumor_idx = (const int*)d_in[11];

    char* ws = (char*)d_ws;
    float* params = (float*)(ws + 0);
    float* w1t    = (float*)(ws + 1024);
    float* w2t    = (float*)(ws + 4096);
    float* kmap   = (float*)(ws + 16384);
    float* pA     = (float*)(ws + 4  * 1024 * 1024);
    float* pB     = (float*)(ws + 12 * 1024 * 1024);
    float* out    = (float*)d_out;

    hipFuncSetAttribute((const void*)step_kernel,
                        hipFuncAttributeMaxDynamicSharedMemorySize, STEP_LDS);

    setup_kernel<<<1, 256, 0, stream>>>(D_raw, chi_raw, cap_logit, w1, w2,
                                        params, w1t, w2t);
    dim3 cgrid(8, 16, B_);
    cnn_kernel<<<cgrid, 256, 0, stream>>>(p0, w1t, b1, w2t, b2, w3, b3, kmap);

    dim3 sgrid(4, 8, B_);
    float* bufs[2] = {pA, pB};
    for (int s = 0; s < STEPS_; ++s) {
        const float* pin = (s == 0) ? p0 : bufs[(s - 1) & 1];
        float* pout = (s == STEPS_ - 1) ? out : bufs[s & 1];
        step_kernel<<<sgrid, 1024, STEP_LDS, stream>>>(pin, pout, kmap, params,
                                                       tumor_idx, s == 0 ? 1 : 0);
    }
}

// Round 6
// 457.767 us; speedup vs baseline: 1.5141x; 1.3358x over previous
//
#include <hip/hip_runtime.h>
#include <math.h>

#define B_ 8
#define K4 4
#define H_ 256
#define W_ 256
#define HID_ 16
#define DT_ 0.1f
#define STEPS_ 12
#define OMEGA_ 0.9f
#define D_MAX_ 2.0f
#define CHI_MAX_ 2.0f
#define HW_ (H_ * W_)

__device__ __forceinline__ int clampi(int v, int lo, int hi) { return min(max(v, lo), hi); }

__device__ __forceinline__ float softplus_f(float x) {
    return fmaxf(x, 0.0f) + log1pf(expf(-fabsf(x)));
}

// exact replication of reference project_simplex row (K=4)
__device__ __forceinline__ void proj4(float v0, float v1, float v2, float v3,
                                      float& o0, float& o1, float& o2, float& o3) {
    float u0 = v0, u1 = v1, u2 = v2, u3 = v3, t;
    t = fmaxf(u0, u1); u1 = fminf(u0, u1); u0 = t;
    t = fmaxf(u2, u3); u3 = fminf(u2, u3); u2 = t;
    t = fmaxf(u0, u2); u2 = fminf(u0, u2); u0 = t;
    t = fmaxf(u1, u3); u3 = fminf(u1, u3); u1 = t;
    t = fmaxf(u1, u2); u2 = fminf(u1, u2); u1 = t;
    float cs1 = u0 + u1;
    float cs2 = cs1 + u2;
    float c0 = u0 - 1.0f;
    float c1 = cs1 - 1.0f;
    float c2 = cs2 - 1.0f;
    int rho = 0;
    if (u1 - c1 / 2.0f > 0.0f) rho = 1;
    if (u2 - c2 / 3.0f > 0.0f) rho = 2;
    if (u3 - (cs2 + u3 - 1.0f) / 4.0f > 0.0f) rho = 3;
    int ri = rho - 1; if (ri < 0) ri = 0;
    float tau = (ri == 0) ? c0 : (ri == 1) ? (c1 / 2.0f) : (c2 / 3.0f);
    float w0 = fmaxf(v0 - tau, 0.0f);
    float w1 = fmaxf(v1 - tau, 0.0f);
    float w2 = fmaxf(v2 - tau, 0.0f);
    float w3 = fmaxf(v3 - tau, 0.0f);
    float inv = 1.0f / (w0 + w1 + w2 + w3 + 1e-8f);
    o0 = w0 * inv; o1 = w1 * inv; o2 = w2 * inv; o3 = w3 * inv;
}

// ---------------- setup: params + weight transpose ----------------
__global__ void setup_kernel(const float* __restrict__ D_raw,
                             const float* __restrict__ chi_raw,
                             const float* __restrict__ cap_logit,
                             const float* __restrict__ w1,
                             const float* __restrict__ w2,
                             float* __restrict__ params,
                             float* __restrict__ w1t,
                             float* __restrict__ w2t) {
    int tid = threadIdx.x;
    if (tid == 0) {
        for (int c = 0; c < K4; ++c) {
            float d = fminf(softplus_f(D_raw[c]) + 1e-8f, D_MAX_);
            params[c]      = d;
            params[6 + c]  = DT_ * d;
            params[10 + c] = OMEGA_ / (1.0f + DT_ * d * 4.0f);
        }
        params[4] = fminf(softplus_f(chi_raw[0]) + 1e-8f, CHI_MAX_);
        float ct = 1.0f / (1.0f + expf(-cap_logit[0]));
        params[5] = fminf(fmaxf(ct, 0.001f), 0.95f);
    }
    for (int i = tid; i < 576; i += 256) {
        int o = i & 15, rest = i >> 4, ic = rest / 9, k = rest % 9;
        w1t[i] = w1[(o * K4 + ic) * 9 + k];
    }
    for (int i = tid; i < 2304; i += 256) {
        int o = i & 15, rest = i >> 4, ic = rest / 9, k = rest % 9;
        w2t[i] = w2[(o * HID_ + ic) * 9 + k];
    }
}

// ---------------- fused CNN, 16x16 tiles (round-3 config + full ic unroll) ----
#define PS2_(c,ry,rx) csmem[((c)*20 + (ry))*24 + (rx)]
#define HS2_(o,ry,rx) csmem[1920 + ((o)*18 + (ry))*21 + (rx)]

__global__ __launch_bounds__(256) void cnn_kernel(const float* __restrict__ p0,
                                                  const float* __restrict__ w1t,
                                                  const float* __restrict__ b1,
                                                  const float* __restrict__ w2t,
                                                  const float* __restrict__ b2,
                                                  const float* __restrict__ w3,
                                                  const float* __restrict__ b3,
                                                  float* __restrict__ kmap) {
    __shared__ float csmem[1920 + 16 * 18 * 21];
    const int tid = threadIdx.x;
    const int tx0 = blockIdx.x * 16, ty0 = blockIdx.y * 16, b = blockIdx.z;

    for (int i = tid; i < 4 * 20 * 20; i += 256) {
        int c = i / 400, r = i % 400;
        int ry = r / 20, rx = r % 20;
        int gy = ty0 + ry - 2, gx = tx0 + rx - 2;
        float v = 0.0f;
        if ((unsigned)gy < 256u && (unsigned)gx < 256u)
            v = p0[(((size_t)b * K4 + c) << 16) + gy * W_ + gx];
        PS2_(c, ry, rx) = v;
    }
    __syncthreads();

    for (int i = tid; i < 18 * 18; i += 256) {
        int iy = i / 18, ixx = i % 18;
        int gy = ty0 + iy - 1, gx = tx0 + ixx - 1;
        bool indom = ((unsigned)gy < 256u) && ((unsigned)gx < 256u);
        float acc[HID_];
#pragma unroll
        for (int o = 0; o < HID_; ++o) acc[o] = b1[o];
#pragma unroll
        for (int ic = 0; ic < K4; ++ic)
#pragma unroll
            for (int ky = 0; ky < 3; ++ky)
#pragma unroll
                for (int kx = 0; kx < 3; ++kx) {
                    float v = PS2_(ic, iy + ky, ixx + kx);
                    const float* wp = w1t + (ic * 9 + ky * 3 + kx) * 16;
#pragma unroll
                    for (int o = 0; o < HID_; ++o)
                        acc[o] = fmaf(wp[o], v, acc[o]);
                }
#pragma unroll
        for (int o = 0; o < HID_; ++o)
            HS2_(o, iy, ixx) = indom ? fmaxf(acc[o], 0.0f) : 0.0f;
    }
    __syncthreads();

    {
        int iy2 = tid >> 4, ix2 = tid & 15;
        float acc[HID_];
#pragma unroll
        for (int o = 0; o < HID_; ++o) acc[o] = b2[o];
#pragma unroll
        for (int ic = 0; ic < HID_; ++ic)
#pragma unroll
            for (int ky = 0; ky < 3; ++ky)
#pragma unroll
                for (int kx = 0; kx < 3; ++kx) {
                    float v = HS2_(ic, iy2 + ky, ix2 + kx);
                    const float* wp = w2t + (ic * 9 + ky * 3 + kx) * 16;
#pragma unroll
                    for (int o = 0; o < HID_; ++o)
                        acc[o] = fmaf(wp[o], v, acc[o]);
                }
        float s = b3[0];
#pragma unroll
        for (int o = 0; o < HID_; ++o)
            s += w3[o] * fmaxf(acc[o], 0.0f);
        float km = 1.0f / (1.0f + expf(-s));
        km = fmaxf(km, 1e-6f);
        kmap[((size_t)b << 16) + (ty0 + iy2) * W_ + tx0 + ix2] = km;
    }
}

// ---------------- proj_rhs: projection (prev step) + rhs (this step) ----------
// 32x32 tiles, 256 threads. PP [4][34][36] = 19.6 KB.
// mode 0: PP = max(p0,0); mode 1: PP = proj(xin); mode 2: pointwise proj only.
#define PP_(c,ry,rx) psm[((c)*34 + (ry))*36 + (rx)]

__global__ __launch_bounds__(256) void proj_rhs_kernel(const float* __restrict__ xin,
                                                       const float* __restrict__ kmap,
                                                       const float* __restrict__ params,
                                                       const int* __restrict__ tumor_idx,
                                                       float* __restrict__ pout,
                                                       float* __restrict__ rhs,
                                                       int mode) {
    const int tid = threadIdx.x;
    const int tx0 = blockIdx.x * 32, ty0 = blockIdx.y * 32, b = blockIdx.z;

    if (mode == 2) {   // final projection, in-place pointwise
        int ry = tid >> 3, g = tid & 7;
        size_t off = ((size_t)(b * K4) << 16) + (ty0 + ry) * W_ + tx0 + 4 * g;
        float4 v0 = *(const float4*)&xin[off];
        float4 v1 = *(const float4*)&xin[off + HW_];
        float4 v2 = *(const float4*)&xin[off + 2 * HW_];
        float4 v3 = *(const float4*)&xin[off + 3 * HW_];
        float a0[4] = {v0.x, v0.y, v0.z, v0.w};
        float a1[4] = {v1.x, v1.y, v1.z, v1.w};
        float a2[4] = {v2.x, v2.y, v2.z, v2.w};
        float a3[4] = {v3.x, v3.y, v3.z, v3.w};
#pragma unroll
        for (int k = 0; k < 4; ++k)
            proj4(a0[k], a1[k], a2[k], a3[k], a0[k], a1[k], a2[k], a3[k]);
        *(float4*)&pout[off]           = make_float4(a0[0], a0[1], a0[2], a0[3]);
        *(float4*)&pout[off + HW_]     = make_float4(a1[0], a1[1], a1[2], a1[3]);
        *(float4*)&pout[off + 2 * HW_] = make_float4(a2[0], a2[1], a2[2], a2[3]);
        *(float4*)&pout[off + 3 * HW_] = make_float4(a3[0], a3[1], a3[2], a3[3]);
        return;
    }

    __shared__ float psm[4 * 34 * 36];

    // build PP on rel [0..33]^2 (clamped reads give edge-replicate)
    for (int i = tid; i < 34 * 34; i += 256) {
        int ry = i / 34, rx = i % 34;
        int gy = clampi(ty0 + ry, 0, 255);
        int gx = clampi(tx0 + rx, 0, 255);
        size_t off = (((size_t)b * K4) << 16) + gy * W_ + gx;
        float v0 = xin[off], v1 = xin[off + HW_], v2 = xin[off + 2 * HW_], v3 = xin[off + 3 * HW_];
        if (mode == 0) {
            v0 = fmaxf(v0, 0.0f); v1 = fmaxf(v1, 0.0f);
            v2 = fmaxf(v2, 0.0f); v3 = fmaxf(v3, 0.0f);
        } else {
            proj4(v0, v1, v2, v3, v0, v1, v2, v3);
        }
        PP_(0, ry, rx) = v0; PP_(1, ry, rx) = v1;
        PP_(2, ry, rx) = v2; PP_(3, ry, rx) = v3;
    }
    __syncthreads();

    // rhs on inner 32x32 (reference arithmetic order); also write p = PP center
    const float chi = params[4], cap = params[5];
    const int ti = tumor_idx[0];
    int ry = tid >> 3, g = tid & 7;
    int gy = ty0 + ry;
    int row1 = clampi(gy + 1, 0, 255) - ty0;
    int row2 = clampi(gy + 2, 0, 255) - ty0;
    float rsvf[4][4], pres[4][4];
#pragma unroll
    for (int k = 0; k < 4; ++k) {
        int rx = 4 * g + k;
        int gx = tx0 + rx;
        int col1 = clampi(gx + 1, 0, 255) - tx0;
        int col2 = clampi(gx + 2, 0, 255) - tx0;
        float pc[4], px1[4], py1[4], g0x[4], g1x[4], g0y[4], g1y[4];
        float s0x = 0.f, s1x = 0.f, s0y = 0.f, s1y = 0.f;
#pragma unroll
        for (int c = 0; c < 4; ++c) {
            float pcv = PP_(c, ry, rx);
            float a   = PP_(c, ry, col1);
            float bb  = PP_(c, ry, col2);
            float d   = PP_(c, row1, rx);
            float e   = PP_(c, row2, rx);
            pc[c] = pcv; px1[c] = a; py1[c] = d;
            g0x[c] = a - pcv;  g1x[c] = bb - a;
            g0y[c] = d - pcv;  g1y[c] = e - d;
            s0x += g0x[c]; s1x += g1x[c]; s0y += g0y[c]; s1y += g1y[c];
        }
        float km = kmap[((size_t)b << 16) + gy * W_ + gx];
#pragma unroll
        for (int c = 0; c < 4; ++c) {
            float fx0 = -chi * pc[c]  * (s0x - g0x[c]);
            float fx1 = -chi * px1[c] * (s1x - g1x[c]);
            float fy0 = -chi * pc[c]  * (s0y - g0y[c]);
            float fy1 = -chi * py1[c] * (s1y - g1y[c]);
            float cross = (fx0 - fx1) + (fy0 - fy1);
            float react = 0.0f;
            if (c == ti) {
                float pt = fminf(fmaxf(pc[c], 0.0f), 1.0f);
                react = km * pt * (1.0f - pt / cap);
            }
            rsvf[c][k] = pc[c] + DT_ * (cross + react);
            pres[c][k] = pc[c];
        }
    }
    size_t off = (((size_t)b * K4) << 16) + gy * W_ + tx0 + 4 * g;
#pragma unroll
    for (int c = 0; c < 4; ++c) {
        *(float4*)&rhs[off + (size_t)c * HW_]  =
            make_float4(rsvf[c][0], rsvf[c][1], rsvf[c][2], rsvf[c][3]);
        *(float4*)&pout[off + (size_t)c * HW_] =
            make_float4(pres[c][0], pres[c][1], pres[c][2], pres[c][3]);
    }
}

// ---------------- jacobi8: per-channel, 64x32 tile, 8 sweeps in LDS ----------
// region rel [-8..71]x[-8..39]; rows rel[-9..40] -> idx 0..49 (0,49 garbage rim),
// cols rel[-9..72] -> idx 3..84 (3,84 garbage rim). XS[2][50][88] = 35.2 KB.
#define JXSTR 88
#define JX_(buf,row,col) jsm[(buf)*(50*JXSTR) + (row)*JXSTR + (col)]

__global__ __launch_bounds__(1024) void jacobi8_kernel(const float* __restrict__ p,
                                                       const float* __restrict__ rhs,
                                                       const float* __restrict__ params,
                                                       float* __restrict__ xk) {
    __shared__ float jsm[2 * 50 * JXSTR];
    const int tid = threadIdx.x;
    const int tx0 = blockIdx.x * 64, ty0 = blockIdx.y * 32;
    const int bc = blockIdx.z;                 // b*4 + c
    const int c  = bc & 3;
    const float* pc_ = p + ((size_t)bc << 16);

    // load region rel [-8..39] x [-8..71] (edge-replicate clamp)
    for (int i = tid; i < 48 * 80; i += 1024) {
        int r = i / 80, x = i % 80;
        int gy = clampi(ty0 + r - 8, 0, 255);
        int gx = clampi(tx0 + x - 8, 0, 255);
        JX_(0, r + 1, x + 4) = pc_[gy * W_ + gx];
    }

    const bool act = (tid < 960);
    const int ry_it = tid / 20, g = tid % 20;
    const int gy = ty0 + ry_it - 8;
    const int gx0 = tx0 + 4 * g - 8;
    const int yc = ry_it + 1;
    const int yu = clampi(gy - 1, 0, 255) - ty0 + 9;
    const int yd = clampi(gy + 1, 0, 255) - ty0 + 9;
    const int ix = 4 + 4 * g;
    const bool lm = (gx0 == 0), rm = (gx0 == 252);
    const float dtD = params[6 + c];
    const float wod = params[10 + c];

    float4 rsv;
    if (act) {
        const float* rr = rhs + ((size_t)bc << 16) + clampi(gy, 0, 255) * W_;
        if (gx0 >= 0 && gx0 <= 252) {
            rsv = *(const float4*)&rr[gx0];
        } else {
            rsv.x = rr[clampi(gx0,     0, 255)];
            rsv.y = rr[clampi(gx0 + 1, 0, 255)];
            rsv.z = rr[clampi(gx0 + 2, 0, 255)];
            rsv.w = rr[clampi(gx0 + 3, 0, 255)];
        }
    }
    __syncthreads();

    float4 ce;
    if (act) ce = *(const float4*)&JX_(0, yc, ix);

#pragma unroll
    for (int j = 0; j < 8; ++j) {
        const int rb = j & 1;
        float4 ov;
        if (act) {
            float4 up = *(const float4*)&JX_(rb, yu, ix);
            float4 dn = *(const float4*)&JX_(rb, yd, ix);
            float lf = JX_(rb, yc, ix - 1);
            float rt = JX_(rb, yc, ix + 4);
            float l0 = lm ? ce.x : lf;
            float r3 = rm ? ce.w : rt;
            {
                float lap = up.x + dn.x + l0 + ce.y - 4.0f * ce.x;
                float r = rsv.x - (ce.x - dtD * lap);
                ov.x = ce.x + wod * r;
            }
            {
                float lap = up.y + dn.y + ce.x + ce.z - 4.0f * ce.y;
                float r = rsv.y - (ce.y - dtD * lap);
                ov.y = ce.y + wod * r;
            }
            {
                float lap = up.z + dn.z + ce.y + ce.w - 4.0f * ce.z;
                float r = rsv.z - (ce.z - dtD * lap);
                ov.z = ce.z + wod * r;
            }
            {
                float lap = up.w + dn.w + ce.z + r3 - 4.0f * ce.w;
                float r = rsv.w - (ce.w - dtD * lap);
                ov.w = ce.w + wod * r;
            }
        }
        if (j < 7) {
            if (act) *(float4*)&JX_((rb ^ 1), yc, ix) = ov;
            __syncthreads();
        }
        if (act) ce = ov;
    }

    // write inner 64x32
    if (act && ry_it >= 8 && ry_it < 40 && g >= 2 && g < 18)
        *(float4*)&xk[((size_t)bc << 16) + gy * W_ + gx0] = ce;
}

extern "C" void kernel_launch(void* const* d_in, const int* in_sizes, int n_in,
                              void* d_out, int out_size, void* d_ws, size_t ws_size,
                              hipStream_t stream) {
    const float* p0        = (const float*)d_in[0];
    const float* D_raw     = (const float*)d_in[1];
    const float* chi_raw   = (const float*)d_in[2];
    const float* cap_logit = (const float*)d_in[4];
    const float* w1        = (const float*)d_in[5];
    const float* b1        = (const float*)d_in[6];
    const float* w2        = (const float*)d_in[7];
    const float* b2        = (const float*)d_in[8];
    const float* w3        = (const float*)d_in[9];
    const float* b3        = (const float*)d_in[10];
    const int*   tumor_idx = (const int*)d_in[11];

    char* ws = (char*)d_ws;
    float* params = (float*)(ws + 0);
    float* w1t    = (float*)(ws + 1024);
    float* w2t    = (float*)(ws + 4096);
    float* kmap   = (float*)(ws + 65536);                 // 2 MB
    float* p      = (float*)(ws + 4  * 1024 * 1024);      // 8 MB
    float* rhs    = (float*)(ws + 12 * 1024 * 1024);      // 8 MB
    float* xk     = (float*)d_out;                        // d_out doubles as xk scratch

    setup_kernel<<<1, 256, 0, stream>>>(D_raw, chi_raw, cap_logit, w1, w2,
                                        params, w1t, w2t);
    dim3 cgrid(16, 16, B_);
    cnn_kernel<<<cgrid, 256, 0, stream>>>(p0, w1t, b1, w2t, b2, w3, b3, kmap);

    dim3 pgrid(8, 8, B_);
    dim3 jgrid(4, 8, B_ * K4);
    for (int s = 0; s < STEPS_; ++s) {
        const float* xin = (s == 0) ? p0 : xk;
        proj_rhs_kernel<<<pgrid, 256, 0, stream>>>(xin, kmap, params, tumor_idx,
                                                   p, rhs, s == 0 ? 0 : 1);
        jacobi8_kernel<<<jgrid, 1024, 0, stream>>>(p, rhs, params, xk);
    }
    // final projection, in-place on d_out
    proj_rhs_kernel<<<pgrid, 256, 0, stream>>>(xk, kmap, params, tumor_idx,
                                               xk, rhs, 2);
}

// Round 7
// 411.077 us; speedup vs baseline: 1.6860x; 1.1136x over previous
//
#include <hip/hip_runtime.h>
#include <math.h>

#define B_ 8
#define K4 4
#define H_ 256
#define W_ 256
#define HID_ 16
#define DT_ 0.1f
#define STEPS_ 12
#define OMEGA_ 0.9f
#define D_MAX_ 2.0f
#define CHI_MAX_ 2.0f
#define HW_ (H_ * W_)

__device__ __forceinline__ int clampi(int v, int lo, int hi) { return min(max(v, lo), hi); }

__device__ __forceinline__ float softplus_f(float x) {
    return fmaxf(x, 0.0f) + log1pf(expf(-fabsf(x)));
}

// exact replication of reference project_simplex row (K=4)
__device__ __forceinline__ void proj4(float v0, float v1, float v2, float v3,
                                      float& o0, float& o1, float& o2, float& o3) {
    float u0 = v0, u1 = v1, u2 = v2, u3 = v3, t;
    t = fmaxf(u0, u1); u1 = fminf(u0, u1); u0 = t;
    t = fmaxf(u2, u3); u3 = fminf(u2, u3); u2 = t;
    t = fmaxf(u0, u2); u2 = fminf(u0, u2); u0 = t;
    t = fmaxf(u1, u3); u3 = fminf(u1, u3); u1 = t;
    t = fmaxf(u1, u2); u2 = fminf(u1, u2); u1 = t;
    float cs1 = u0 + u1;
    float cs2 = cs1 + u2;
    float c0 = u0 - 1.0f;
    float c1 = cs1 - 1.0f;
    float c2 = cs2 - 1.0f;
    int rho = 0;
    if (u1 - c1 / 2.0f > 0.0f) rho = 1;
    if (u2 - c2 / 3.0f > 0.0f) rho = 2;
    if (u3 - (cs2 + u3 - 1.0f) / 4.0f > 0.0f) rho = 3;
    int ri = rho - 1; if (ri < 0) ri = 0;
    float tau = (ri == 0) ? c0 : (ri == 1) ? (c1 / 2.0f) : (c2 / 3.0f);
    float w0 = fmaxf(v0 - tau, 0.0f);
    float w1 = fmaxf(v1 - tau, 0.0f);
    float w2 = fmaxf(v2 - tau, 0.0f);
    float w3 = fmaxf(v3 - tau, 0.0f);
    float inv = 1.0f / (w0 + w1 + w2 + w3 + 1e-8f);
    o0 = w0 * inv; o1 = w1 * inv; o2 = w2 * inv; o3 = w3 * inv;
}

// ---------------- setup: params + weight transpose ----------------
__global__ void setup_kernel(const float* __restrict__ D_raw,
                             const float* __restrict__ chi_raw,
                             const float* __restrict__ cap_logit,
                             const float* __restrict__ w1,
                             const float* __restrict__ w2,
                             float* __restrict__ params,
                             float* __restrict__ w1t,
                             float* __restrict__ w2t) {
    int tid = threadIdx.x;
    if (tid == 0) {
        for (int c = 0; c < K4; ++c) {
            float d = fminf(softplus_f(D_raw[c]) + 1e-8f, D_MAX_);
            params[c]      = d;
            params[6 + c]  = DT_ * d;
            params[10 + c] = OMEGA_ / (1.0f + DT_ * d * 4.0f);
        }
        params[4] = fminf(softplus_f(chi_raw[0]) + 1e-8f, CHI_MAX_);
        float ct = 1.0f / (1.0f + expf(-cap_logit[0]));
        params[5] = fminf(fmaxf(ct, 0.001f), 0.95f);
    }
    for (int i = tid; i < 576; i += 256) {
        int o = i & 15, rest = i >> 4, ic = rest / 9, k = rest % 9;
        w1t[i] = w1[(o * K4 + ic) * 9 + k];
    }
    for (int i = tid; i < 2304; i += 256) {
        int o = i & 15, rest = i >> 4, ic = rest / 9, k = rest % 9;
        w2t[i] = w2[(o * HID_ + ic) * 9 + k];
    }
}

// ---------------- fused CNN, 16x16 tiles (round-3 body, HS stride 24) ----
#define PS2_(c,ry,rx) csmem[((c)*20 + (ry))*24 + (rx)]
#define HS2_(o,ry,rx) csmem[1920 + ((o)*18 + (ry))*24 + (rx)]

__global__ __launch_bounds__(256) void cnn_kernel(const float* __restrict__ p0,
                                                  const float* __restrict__ w1t,
                                                  const float* __restrict__ b1,
                                                  const float* __restrict__ w2t,
                                                  const float* __restrict__ b2,
                                                  const float* __restrict__ w3,
                                                  const float* __restrict__ b3,
                                                  float* __restrict__ kmap) {
    __shared__ float csmem[1920 + 16 * 18 * 24];
    const int tid = threadIdx.x;
    const int tx0 = blockIdx.x * 16, ty0 = blockIdx.y * 16, b = blockIdx.z;

    for (int i = tid; i < 4 * 20 * 20; i += 256) {
        int c = i / 400, r = i % 400;
        int ry = r / 20, rx = r % 20;
        int gy = ty0 + ry - 2, gx = tx0 + rx - 2;
        float v = 0.0f;
        if ((unsigned)gy < 256u && (unsigned)gx < 256u)
            v = p0[(((size_t)b * K4 + c) << 16) + gy * W_ + gx];
        PS2_(c, ry, rx) = v;
    }
    __syncthreads();

    for (int i = tid; i < 18 * 18; i += 256) {
        int iy = i / 18, ixx = i % 18;
        int gy = ty0 + iy - 1, gx = tx0 + ixx - 1;
        bool indom = ((unsigned)gy < 256u) && ((unsigned)gx < 256u);
        float acc[HID_];
#pragma unroll
        for (int o = 0; o < HID_; ++o) acc[o] = b1[o];
        for (int ic = 0; ic < K4; ++ic)
            for (int ky = 0; ky < 3; ++ky)
#pragma unroll
                for (int kx = 0; kx < 3; ++kx) {
                    float v = PS2_(ic, iy + ky, ixx + kx);
                    const float* wp = w1t + (ic * 9 + ky * 3 + kx) * 16;
#pragma unroll
                    for (int o = 0; o < HID_; ++o)
                        acc[o] = fmaf(wp[o], v, acc[o]);
                }
#pragma unroll
        for (int o = 0; o < HID_; ++o)
            HS2_(o, iy, ixx) = indom ? fmaxf(acc[o], 0.0f) : 0.0f;
    }
    __syncthreads();

    {
        int iy2 = tid >> 4, ix2 = tid & 15;
        float acc[HID_];
#pragma unroll
        for (int o = 0; o < HID_; ++o) acc[o] = b2[o];
        for (int ic = 0; ic < HID_; ++ic)
            for (int ky = 0; ky < 3; ++ky)
#pragma unroll
                for (int kx = 0; kx < 3; ++kx) {
                    float v = HS2_(ic, iy2 + ky, ix2 + kx);
                    const float* wp = w2t + (ic * 9 + ky * 3 + kx) * 16;
#pragma unroll
                    for (int o = 0; o < HID_; ++o)
                        acc[o] = fmaf(wp[o], v, acc[o]);
                }
        float s = b3[0];
#pragma unroll
        for (int o = 0; o < HID_; ++o)
            s += w3[o] * fmaxf(acc[o], 0.0f);
        float km = 1.0f / (1.0f + expf(-s));
        km = fmaxf(km, 1e-6f);
        kmap[((size_t)b << 16) + (ty0 + iy2) * W_ + tx0 + ix2] = km;
    }
}

// ---------------- proj_rhs: projection (prev step) + rhs (this step) ----------
// 16x16 tiles, 256 threads, grid 2048 -> 8 blocks/CU. PP [4][18][20] = 5.8 KB.
// mode 0: PP = max(p0,0); mode 1: PP = proj(xin); mode 2: pointwise proj only.
#define PP_(c,ry,rx) psm[((c)*18 + (ry))*20 + (rx)]

__global__ __launch_bounds__(256) void proj_rhs_kernel(const float* __restrict__ xin,
                                                       const float* __restrict__ kmap,
                                                       const float* __restrict__ params,
                                                       const int* __restrict__ tumor_idx,
                                                       float* __restrict__ pout,
                                                       float* __restrict__ rhs,
                                                       int mode) {
    const int tid = threadIdx.x;
    const int tx0 = blockIdx.x * 16, ty0 = blockIdx.y * 16, b = blockIdx.z;

    if (mode == 2) {   // final projection, in-place pointwise
        int ry = tid >> 4, rx = tid & 15;
        size_t off = ((size_t)(b * K4) << 16) + (ty0 + ry) * W_ + tx0 + rx;
        float v0 = xin[off];
        float v1 = xin[off + HW_];
        float v2 = xin[off + 2 * HW_];
        float v3 = xin[off + 3 * HW_];
        proj4(v0, v1, v2, v3, v0, v1, v2, v3);
        pout[off]           = v0;
        pout[off + HW_]     = v1;
        pout[off + 2 * HW_] = v2;
        pout[off + 3 * HW_] = v3;
        return;
    }

    __shared__ float psm[4 * 18 * 20];

    // build PP on rel [0..17]^2 (clamped reads give edge-replicate)
    for (int i = tid; i < 18 * 18; i += 256) {
        int ry = i / 18, rx = i % 18;
        int gy = clampi(ty0 + ry, 0, 255);
        int gx = clampi(tx0 + rx, 0, 255);
        size_t off = (((size_t)b * K4) << 16) + gy * W_ + gx;
        float v0 = xin[off], v1 = xin[off + HW_];
        float v2 = xin[off + 2 * HW_], v3 = xin[off + 3 * HW_];
        if (mode == 0) {
            v0 = fmaxf(v0, 0.0f); v1 = fmaxf(v1, 0.0f);
            v2 = fmaxf(v2, 0.0f); v3 = fmaxf(v3, 0.0f);
        } else {
            proj4(v0, v1, v2, v3, v0, v1, v2, v3);
        }
        PP_(0, ry, rx) = v0; PP_(1, ry, rx) = v1;
        PP_(2, ry, rx) = v2; PP_(3, ry, rx) = v3;
    }
    __syncthreads();

    // rhs on 16x16, 1 px/thread (reference arithmetic order); also write p
    const float chi = params[4], cap = params[5];
    const int ti = tumor_idx[0];
    int ry = tid >> 4, rx = tid & 15;
    int gy = ty0 + ry, gx = tx0 + rx;
    int row1 = clampi(gy + 1, 0, 255) - ty0;
    int row2 = clampi(gy + 2, 0, 255) - ty0;
    int col1 = clampi(gx + 1, 0, 255) - tx0;
    int col2 = clampi(gx + 2, 0, 255) - tx0;
    float pc[4], px1[4], py1[4], g0x[4], g1x[4], g0y[4], g1y[4];
    float s0x = 0.f, s1x = 0.f, s0y = 0.f, s1y = 0.f;
#pragma unroll
    for (int c = 0; c < 4; ++c) {
        float pcv = PP_(c, ry, rx);
        float a   = PP_(c, ry, col1);
        float bb  = PP_(c, ry, col2);
        float d   = PP_(c, row1, rx);
        float e   = PP_(c, row2, rx);
        pc[c] = pcv; px1[c] = a; py1[c] = d;
        g0x[c] = a - pcv;  g1x[c] = bb - a;
        g0y[c] = d - pcv;  g1y[c] = e - d;
        s0x += g0x[c]; s1x += g1x[c]; s0y += g0y[c]; s1y += g1y[c];
    }
    float km = kmap[((size_t)b << 16) + gy * W_ + gx];
    size_t off = (((size_t)b * K4) << 16) + gy * W_ + gx;
#pragma unroll
    for (int c = 0; c < 4; ++c) {
        float fx0 = -chi * pc[c]  * (s0x - g0x[c]);
        float fx1 = -chi * px1[c] * (s1x - g1x[c]);
        float fy0 = -chi * pc[c]  * (s0y - g0y[c]);
        float fy1 = -chi * py1[c] * (s1y - g1y[c]);
        float cross = (fx0 - fx1) + (fy0 - fy1);
        float react = 0.0f;
        if (c == ti) {
            float pt = fminf(fmaxf(pc[c], 0.0f), 1.0f);
            react = km * pt * (1.0f - pt / cap);
        }
        rhs[off + (size_t)c * HW_]  = pc[c] + DT_ * (cross + react);
        pout[off + (size_t)c * HW_] = pc[c];
    }
}

// ---------------- jacobi8: per-channel, 64x32 tile, 8 sweeps in LDS ----------
#define JXSTR 88
#define JX_(buf,row,col) jsm[(buf)*(50*JXSTR) + (row)*JXSTR + (col)]

__global__ __launch_bounds__(1024, 8) void jacobi8_kernel(const float* __restrict__ p,
                                                          const float* __restrict__ rhs,
                                                          const float* __restrict__ params,
                                                          float* __restrict__ xk) {
    __shared__ float jsm[2 * 50 * JXSTR];
    const int tid = threadIdx.x;
    const int tx0 = blockIdx.x * 64, ty0 = blockIdx.y * 32;
    const int bc = blockIdx.z;                 // b*4 + c
    const int c  = bc & 3;
    const float* pc_ = p + ((size_t)bc << 16);

    // load region rel [-8..39] x [-8..71] (edge-replicate clamp)
    for (int i = tid; i < 48 * 80; i += 1024) {
        int r = i / 80, x = i % 80;
        int gy = clampi(ty0 + r - 8, 0, 255);
        int gx = clampi(tx0 + x - 8, 0, 255);
        JX_(0, r + 1, x + 4) = pc_[gy * W_ + gx];
    }

    const bool act = (tid < 960);
    const int ry_it = tid / 20, g = tid % 20;
    const int gy = ty0 + ry_it - 8;
    const int gx0 = tx0 + 4 * g - 8;
    const int yc = ry_it + 1;
    const int yu = clampi(gy - 1, 0, 255) - ty0 + 9;
    const int yd = clampi(gy + 1, 0, 255) - ty0 + 9;
    const int ix = 4 + 4 * g;
    const bool lm = (gx0 == 0), rm = (gx0 == 252);
    const float dtD = params[6 + c];
    const float wod = params[10 + c];

    float4 rsv;
    if (act) {
        const float* rr = rhs + ((size_t)bc << 16) + clampi(gy, 0, 255) * W_;
        if (gx0 >= 0 && gx0 <= 252) {
            rsv = *(const float4*)&rr[gx0];
        } else {
            rsv.x = rr[clampi(gx0,     0, 255)];
            rsv.y = rr[clampi(gx0 + 1, 0, 255)];
            rsv.z = rr[clampi(gx0 + 2, 0, 255)];
            rsv.w = rr[clampi(gx0 + 3, 0, 255)];
        }
    }
    __syncthreads();

    float4 ce;
    if (act) ce = *(const float4*)&JX_(0, yc, ix);

#pragma unroll
    for (int j = 0; j < 8; ++j) {
        const int rb = j & 1;
        float4 ov;
        if (act) {
            float4 up = *(const float4*)&JX_(rb, yu, ix);
            float4 dn = *(const float4*)&JX_(rb, yd, ix);
            float lf = JX_(rb, yc, ix - 1);
            float rt = JX_(rb, yc, ix + 4);
            float l0 = lm ? ce.x : lf;
            float r3 = rm ? ce.w : rt;
            {
                float lap = up.x + dn.x + l0 + ce.y - 4.0f * ce.x;
                float r = rsv.x - (ce.x - dtD * lap);
                ov.x = ce.x + wod * r;
            }
            {
                float lap = up.y + dn.y + ce.x + ce.z - 4.0f * ce.y;
                float r = rsv.y - (ce.y - dtD * lap);
                ov.y = ce.y + wod * r;
            }
            {
                float lap = up.z + dn.z + ce.y + ce.w - 4.0f * ce.z;
                float r = rsv.z - (ce.z - dtD * lap);
                ov.z = ce.z + wod * r;
            }
            {
                float lap = up.w + dn.w + ce.z + r3 - 4.0f * ce.w;
                float r = rsv.w - (ce.w - dtD * lap);
                ov.w = ce.w + wod * r;
            }
        }
        if (j < 7) {
            if (act) *(float4*)&JX_((rb ^ 1), yc, ix) = ov;
            __syncthreads();
        }
        if (act) ce = ov;
    }

    // write inner 64x32
    if (act && ry_it >= 8 && ry_it < 40 && g >= 2 && g < 18)
        *(float4*)&xk[((size_t)bc << 16) + gy * W_ + gx0] = ce;
}

extern "C" void kernel_launch(void* const* d_in, const int* in_sizes, int n_in,
                              void* d_out, int out_size, void* d_ws, size_t ws_size,
                              hipStream_t stream) {
    const float* p0        = (const float*)d_in[0];
    const float* D_raw     = (const float*)d_in[1];
    const float* chi_raw   = (const float*)d_in[2];
    const float* cap_logit = (const float*)d_in[4];
    const float* w1        = (const float*)d_in[5];
    const float* b1        = (const float*)d_in[6];
    const float* w2        = (const float*)d_in[7];
    const float* b2        = (const float*)d_in[8];
    const float* w3        = (const float*)d_in[9];
    const float* b3        = (const float*)d_in[10];
    const int*   tumor_idx = (const int*)d_in[11];

    char* ws = (char*)d_ws;
    float* params = (float*)(ws + 0);
    float* w1t    = (float*)(ws + 1024);
    float* w2t    = (float*)(ws + 4096);
    float* kmap   = (float*)(ws + 65536);                 // 2 MB
    float* p      = (float*)(ws + 4  * 1024 * 1024);      // 8 MB
    float* rhs    = (float*)(ws + 12 * 1024 * 1024);      // 8 MB
    float* xk     = (float*)d_out;                        // d_out doubles as xk scratch

    setup_kernel<<<1, 256, 0, stream>>>(D_raw, chi_raw, cap_logit, w1, w2,
                                        params, w1t, w2t);
    dim3 cgrid(16, 16, B_);
    cnn_kernel<<<cgrid, 256, 0, stream>>>(p0, w1t, b1, w2t, b2, w3, b3, kmap);

    dim3 pgrid(16, 16, B_);
    dim3 jgrid(4, 8, B_ * K4);
    for (int s = 0; s < STEPS_; ++s) {
        const float* xin = (s == 0) ? p0 : xk;
        proj_rhs_kernel<<<pgrid, 256, 0, stream>>>(xin, kmap, params, tumor_idx,
                                                   p, rhs, s == 0 ? 0 : 1);
        jacobi8_kernel<<<jgrid, 1024, 0, stream>>>(p, rhs, params, xk);
    }
    // final projection, in-place on d_out
    proj_rhs_kernel<<<pgrid, 256, 0, stream>>>(xk, kmap, params, tumor_idx,
                                               xk, rhs, 2);
}